// Round 4
// baseline (9237.936 us; speedup 1.0000x reference)
//
#include <hip/hip_runtime.h>

#define DT 0.01f
#define NH 512
#define T_STEPS 1024
#define NB 128
#define SLICE 64

typedef _Float16 h2v __attribute__((ext_vector_type(2)));
typedef _Float16 h8v __attribute__((ext_vector_type(8)));

#if defined(__has_builtin)
#if __has_builtin(__builtin_amdgcn_fdot2)
#define HAVE_FDOT2 1
#endif
#endif

#ifdef HAVE_FDOT2
#define FDOT2(a, b, c) __builtin_amdgcn_fdot2((a), (b), (c), false)
#else
static __device__ __forceinline__ float FDOT2(h2v a, h2v b, float c) {
    return c + (float)a[0] * (float)b[0] + (float)a[1] * (float)b[1];
}
#endif

static __device__ __forceinline__ unsigned long long pack2f(float a, float b) {
    union { float f[2]; unsigned long long u; } x;
    x.f[0] = a; x.f[1] = b; return x.u;
}
static __device__ __forceinline__ void unpack2f(unsigned long long u, float& a, float& b) {
    union { unsigned long long u; float f[2]; } x;
    x.u = u; a = x.f[0]; b = x.f[1];
}

// LDS layout (bytes)
#define O_W1 0        // [64 i8][64 jj] h8v = 64 KB   staging only; preloaded to VGPRs
#define O_W2 65536    // [512 p][8 k^sw] h8v = 64 KB  w2p: w[p][jm+k*8+e] (XOR-swizzled)
#define O_HY 131072   // [4 r][512 i] fp16 = 4 KB     full hy (redundant per member)
#define O_S  135168   // [4 r][64 j] fp16 = 512 B     own s slice
#define LDS_BYTES 135680

// ---------- kernel 1: i2h = tanh(x @ x2h) -> written into d_out all_states slots ----------
__global__ __launch_bounds__(512) void i2h_kernel(const float* __restrict__ x,
                                                  const float* __restrict__ x2h,
                                                  float* __restrict__ out) {
    __shared__ __align__(16) float xs[16 * 64];
    int bt0 = blockIdx.x * 16;
    int tid = threadIdx.x;
    xs[tid]       = x[(size_t)bt0 * 64 + tid];
    xs[tid + 512] = x[(size_t)bt0 * 64 + tid + 512];
    __syncthreads();

    float acc[16];
    #pragma unroll
    for (int r = 0; r < 16; ++r) acc[r] = 0.f;

    for (int i4 = 0; i4 < 16; ++i4) {
        float w0 = x2h[(i4 * 4 + 0) * 512 + tid];
        float w1 = x2h[(i4 * 4 + 1) * 512 + tid];
        float w2 = x2h[(i4 * 4 + 2) * 512 + tid];
        float w3 = x2h[(i4 * 4 + 3) * 512 + tid];
        #pragma unroll
        for (int r = 0; r < 16; ++r) {
            float4 xv = *(const float4*)&xs[r * 64 + i4 * 4];
            acc[r] += xv.x * w0 + xv.y * w1 + xv.z * w2 + xv.w * w3;
        }
    }
    #pragma unroll
    for (int r = 0; r < 16; ++r)
        out[(size_t)(bt0 + r) * 512 + tid] = tanhf(acc[r]);
}

// ---------- kernel 2: recurrence. 32 groups x 8 members.
// Pass-1 weights VGPR-resident (step-invariant per lane). Exchange: plain fp32 slot
// stores (2 u64/thread, no RMW) -> syncthreads drain -> per-member release flag ->
// 8-thread spin -> batched 16-load read + fixed-order fp32 sum (bit-deterministic).
// Parity double-buffer; 4 barriers/step. ----------
__global__ __launch_bounds__(512, 1) void recur6(const float* __restrict__ h2h,
                                                 const float* __restrict__ bias,
                                                 float* __restrict__ out,
                                                 unsigned long long* __restrict__ recbuf,
                                                 unsigned int* __restrict__ flags) {
    extern __shared__ unsigned char lds[];
    h8v* w1p      = (h8v*)(lds + O_W1);
    h8v* w2p      = (h8v*)(lds + O_W2);
    _Float16* hyH = (_Float16*)(lds + O_HY);
    _Float16* stg = (_Float16*)(lds + O_S);

    const int tid = threadIdx.x;
    const int m   = blockIdx.x >> 5;   // member: bid%8 == G%8 for all members -> same XCD L2
    const int G   = blockIdx.x & 31;   // group (4 batch rows)
    const int jm  = m * SLICE;
    const int p   = tid;               // pass-2 / state column (0..511)

    // pass-1 thread mapping: wave w -> row r1, 32-j block; lane bit5 splits i into halves
    const int w    = tid >> 6;
    const int r1   = w >> 1;
    const int jj1  = (w & 1) * 32 + (tid & 31);
    const int half = (tid >> 5) & 1;

    // ---- one-time: load + fp16-convert weight col-slice into LDS, two layouts ----
    for (int it = 0; it < 8; ++it) {
        int gidx = it * 512 + tid;
        int i8 = gidx >> 6, j = gidx & 63;          // lanes run over j -> coalesced
        h8v wv;
        #pragma unroll
        for (int e = 0; e < 8; ++e)
            wv[e] = (_Float16)h2h[(size_t)(i8 * 8 + e) * NH + jm + j];
        w1p[i8 * 64 + j] = wv;
    }
    for (int it = 0; it < 8; ++it) {
        int gidx = it * 512 + tid;
        int pr = gidx >> 3, k = gidx & 7;           // lanes run over k,e -> coalesced
        const float* rp = h2h + (size_t)pr * NH + jm + k * 8;
        h8v wv;
        #pragma unroll
        for (int e = 0; e < 8; ++e) wv[e] = (_Float16)rp[e];
        w2p[pr * 8 + (k ^ (pr & 7))] = wv;          // XOR swizzle: conflict-free row reads
    }

    // zero hy for t=0
    #pragma unroll
    for (int r = 0; r < 4; ++r) hyH[r * NH + p] = (_Float16)0.f;

    __syncthreads();   // staging complete

    // ---- preload pass-1 weights into VGPRs: step-invariant per lane (half, jj1) ----
    h8v w1r[32];
    #pragma unroll
    for (int kk = 0; kk < 32; ++kk)
        w1r[kk] = w1p[(half * 32 + kk) * 64 + jj1];

    // exchange buffers: [G][par][m][pack][512 p] u64
    unsigned long long* rb = recbuf + (size_t)G * 16384;
    unsigned int* flagBase = flags + G * 128;    // 8 members x 16 u32 (64 B pad)

    const float bj1 = bias[jm + jj1];

    const float* ivBase = out + (size_t)(4 * G) * T_STEPS * NH + p;
    float* outBase      = out + (size_t)(4 * G) * T_STEPS * NH + p;
    const bool writer = ((p >> 6) == m);   // this member writes cols [jm, jm+64)

    float hy[4] = {0.f, 0.f, 0.f, 0.f};
    float hz[4] = {0.f, 0.f, 0.f, 0.f};

    // prologue: iv(0)
    float iv[4];
    #pragma unroll
    for (int r = 0; r < 4; ++r) iv[r] = ivBase[(size_t)r * T_STEPS * NH];

    for (int t = 0; t < T_STEPS; ++t) {
        // prefetch iv(t+1): slot untouched until peers pass barrier(t), which requires our
        // flag(t), which follows our syncthreads drain of these loads -> race-free
        float ivn[4] = {0.f, 0.f, 0.f, 0.f};
        if (t + 1 < T_STEPS) {
            #pragma unroll
            for (int r = 0; r < 4; ++r)
                ivn[r] = ivBase[((size_t)r * T_STEPS + (t + 1)) * NH];
        }

        // ---- pass 1: z[r1][jm+jj1], weights in VGPRs, hy via LDS broadcast ----
        {
            float acc = 0.f;
            const _Float16* hyRow = hyH + r1 * NH + half * 256;   // lane-uniform per half
            #pragma unroll
            for (int kk = 0; kk < 32; ++kk) {
                h8v wv = w1r[kk];
                h8v av = *(const h8v*)(hyRow + kk * 8);
                h2v wA = {wv[0], wv[1]}, wB = {wv[2], wv[3]},
                    wC = {wv[4], wv[5]}, wD = {wv[6], wv[7]};
                h2v aA = {av[0], av[1]}, aB = {av[2], av[3]},
                    aC = {av[4], av[5]}, aD = {av[6], av[7]};
                acc = FDOT2(wA, aA, acc); acc = FDOT2(wB, aB, acc);
                acc = FDOT2(wC, aC, acc); acc = FDOT2(wD, aD, acc);
            }
            float tot = acc + __shfl_xor(acc, 32);
            float sv = tanhf(tot + bj1);
            if (half == 0) stg[r1 * 64 + jj1] = (_Float16)sv;
        }
        __syncthreads();   // A: stg ready

        // ---- pass 2: partial rec[r][p] over own j-slice, for ALL 512 p ----
        float acc[4] = {0.f, 0.f, 0.f, 0.f};
        {
            const int sw = p & 7;
            #pragma unroll
            for (int k = 0; k < 8; ++k) {
                h8v wv = w2p[p * 8 + (k ^ sw)];
                h2v wA = {wv[0], wv[1]}, wB = {wv[2], wv[3]},
                    wC = {wv[4], wv[5]}, wD = {wv[6], wv[7]};
                #pragma unroll
                for (int r = 0; r < 4; ++r) {
                    h8v sv = *(const h8v*)(stg + r * 64 + k * 8);   // lane-uniform broadcast
                    h2v sA = {sv[0], sv[1]}, sB = {sv[2], sv[3]},
                        sC = {sv[4], sv[5]}, sD = {sv[6], sv[7]};
                    float a = acc[r];
                    a = FDOT2(wA, sA, a); a = FDOT2(wB, sB, a);
                    a = FDOT2(wC, sC, a); a = FDOT2(wD, sD, a);
                    acc[r] = a;
                }
            }
        }

        // ---- publish partials: contention-free slot stores (agent scope) ----
        const int par = t & 1;
        unsigned long long* myslot = rb + par * 8192 + m * 1024 + p;
        __hip_atomic_store(myslot, pack2f(acc[0], acc[1]),
                           __ATOMIC_RELAXED, __HIP_MEMORY_SCOPE_AGENT);
        __hip_atomic_store(myslot + 512, pack2f(acc[2], acc[3]),
                           __ATOMIC_RELAXED, __HIP_MEMORY_SCOPE_AGENT);

        __syncthreads();   // B: per-wave vmcnt(0) drain -> all member stores visible-ordered
        if (tid == 0)
            __hip_atomic_store(flagBase + m * 16, (unsigned int)(t + 1),
                               __ATOMIC_RELEASE, __HIP_MEMORY_SCOPE_AGENT);
        if (tid < 8) {
            const unsigned int* fp = flagBase + tid * 16;
            while (__hip_atomic_load(fp, __ATOMIC_ACQUIRE, __HIP_MEMORY_SCOPE_AGENT)
                   <= (unsigned int)t)
                __builtin_amdgcn_s_sleep(1);
        }
        __syncthreads();   // C: all 8 members' partials visible

        // ---- batched read of all 8 members' partials; fixed-order deterministic sum ----
        const unsigned long long* lbase = rb + par * 8192 + p;
        unsigned long long va[8], vb[8];
        #pragma unroll
        for (int mm = 0; mm < 8; ++mm) {
            va[mm] = __hip_atomic_load(lbase + mm * 1024, __ATOMIC_RELAXED,
                                       __HIP_MEMORY_SCOPE_AGENT);
            vb[mm] = __hip_atomic_load(lbase + mm * 1024 + 512, __ATOMIC_RELAXED,
                                       __HIP_MEMORY_SCOPE_AGENT);
        }
        float rec0 = 0.f, rec1 = 0.f, rec2 = 0.f, rec3 = 0.f;
        #pragma unroll
        for (int mm = 0; mm < 8; ++mm) {
            float a, b;
            unpack2f(va[mm], a, b); rec0 += a; rec1 += b;
            unpack2f(vb[mm], a, b); rec2 += a; rec3 += b;
        }

        // ---- identical full update on every member ----
        float rec[4] = {rec0, rec1, rec2, rec3};
        #pragma unroll
        for (int r = 0; r < 4; ++r) {
            hz[r] = hz[r] + DT * (iv[r] - rec[r] - hy[r] - hz[r]);
            hy[r] = hy[r] + DT * hz[r];
        }
        if (writer) {
            #pragma unroll
            for (int r = 0; r < 4; ++r)
                outBase[((size_t)r * T_STEPS + t) * NH] = hy[r];
        }
        #pragma unroll
        for (int r = 0; r < 4; ++r) {
            hyH[r * NH + p] = (_Float16)hy[r];
            iv[r] = ivn[r];
        }
        __syncthreads();   // D: hyH ready for next pass 1
    }

    // hy_f (concatenated after all_states)
    if (writer) {
        #pragma unroll
        for (int r = 0; r < 4; ++r)
            out[(size_t)NB * T_STEPS * NH + (size_t)(4 * G + r) * NH + p] = hy[r];
    }
}

// ---------- launch ----------
extern "C" void kernel_launch(void* const* d_in, const int* in_sizes, int n_in,
                              void* d_out, int out_size, void* d_ws, size_t ws_size,
                              hipStream_t stream) {
    const float* x    = (const float*)d_in[0];   // [128,1024,64]
    const float* x2h  = (const float*)d_in[1];   // [64,512]
    const float* h2h  = (const float*)d_in[2];   // [512,512]
    const float* bias = (const float*)d_in[3];   // [512]
    float* out = (float*)d_out;

    // ws layout: flags 64 KB (32 groups x 8 x 64 B) | recbuf 4 MB (32 x 16384 u64)
    unsigned int* flags        = (unsigned int*)d_ws;
    unsigned long long* recbuf = (unsigned long long*)((char*)d_ws + 65536);

    hipMemsetAsync(d_ws, 0, 65536, stream);   // flags only; recbuf is store-before-read

    i2h_kernel<<<8192, 512, 0, stream>>>(x, x2h, out);

    hipFuncSetAttribute((const void*)recur6,
                        hipFuncAttributeMaxDynamicSharedMemorySize, LDS_BYTES);
    recur6<<<256, 512, LDS_BYTES, stream>>>(h2h, bias, out, recbuf, flags);
}

// Round 5
// 8059.476 us; speedup vs baseline: 1.1462x; 1.1462x over previous
//
#include <hip/hip_runtime.h>

#define DT 0.01f
#define NH 512
#define T_STEPS 1024
#define NB 128
#define SLICE 64
#define SCALE_F 131072.0f              // 2^17 fixed-point scale
#define INV_SCALE 7.62939453125e-6f    // 2^-17
#define BIGC (1 << 21)                 // per-member field bias (keeps fields >= 0)
#define BIAS8 (8 << 21)                // total bias after 8 members

typedef _Float16 h2v __attribute__((ext_vector_type(2)));
typedef _Float16 h8v __attribute__((ext_vector_type(8)));

#if defined(__has_builtin)
#if __has_builtin(__builtin_amdgcn_fdot2)
#define HAVE_FDOT2 1
#endif
#endif

#ifdef HAVE_FDOT2
#define FDOT2(a, b, c) __builtin_amdgcn_fdot2((a), (b), (c), false)
#else
static __device__ __forceinline__ float FDOT2(h2v a, h2v b, float c) {
    return c + (float)a[0] * (float)b[0] + (float)a[1] * (float)b[1];
}
#endif

// LDS layout (bytes)
#define O_W1 0        // [64 i8][64 jj] h8v = 64 KB   w1p: w[i8*8+e][jm+jj]   (col-slice, col-major)
#define O_W2 65536    // [512 p][8 k^sw] h8v = 64 KB  w2p: w[p][jm+k*8+e]     (col-slice, row-major, XOR-swizzled)
#define O_HY 131072   // [4 r][512 i] fp16 = 4 KB     full hy (redundant per member)
#define O_S  135168   // [4 r][64 j] fp16 = 512 B     own s slice
#define LDS_BYTES 135680

// ---------- kernel 1: i2h = tanh(x @ x2h) -> written into d_out all_states slots ----------
__global__ __launch_bounds__(512) void i2h_kernel(const float* __restrict__ x,
                                                  const float* __restrict__ x2h,
                                                  float* __restrict__ out) {
    __shared__ __align__(16) float xs[16 * 64];
    int bt0 = blockIdx.x * 16;
    int tid = threadIdx.x;
    xs[tid]       = x[(size_t)bt0 * 64 + tid];
    xs[tid + 512] = x[(size_t)bt0 * 64 + tid + 512];
    __syncthreads();

    float acc[16];
    #pragma unroll
    for (int r = 0; r < 16; ++r) acc[r] = 0.f;

    for (int i4 = 0; i4 < 16; ++i4) {
        float w0 = x2h[(i4 * 4 + 0) * 512 + tid];
        float w1 = x2h[(i4 * 4 + 1) * 512 + tid];
        float w2 = x2h[(i4 * 4 + 2) * 512 + tid];
        float w3 = x2h[(i4 * 4 + 3) * 512 + tid];
        #pragma unroll
        for (int r = 0; r < 16; ++r) {
            float4 xv = *(const float4*)&xs[r * 64 + i4 * 4];
            acc[r] += xv.x * w0 + xv.y * w1 + xv.z * w2 + xv.w * w3;
        }
    }
    #pragma unroll
    for (int r = 0; r < 16; ++r)
        out[(size_t)(bt0 + r) * 512 + tid] = tanhf(acc[r]);
}

// ---------- kernel 2: recurrence. 32 groups x 8 members; ONE round trip per step.
// Exchange: u64 atomic adds carrying (1<<50) + (biased dRow_a << 25) + biased dRow_b.
// Bias 2^21/member keeps both 25-bit fields non-negative -> no borrow into count bits
// -> poll check is raw (v >> 50) >= expc, decode is mask+subtract. Slot pair adjacent
// (one cache line). Writer's out store deferred one step (drains under poll).
// Pass-1: LDS weights (recur5-proven), bit5 i-split, shfl_xor(32). 2 barriers/step. ----------
__global__ __launch_bounds__(512, 1) void recur7(const float* __restrict__ h2h,
                                                 const float* __restrict__ bias,
                                                 float* __restrict__ out,
                                                 unsigned long long* __restrict__ recbuf) {
    extern __shared__ unsigned char lds[];
    h8v* w1p      = (h8v*)(lds + O_W1);
    h8v* w2p      = (h8v*)(lds + O_W2);
    _Float16* hyH = (_Float16*)(lds + O_HY);
    _Float16* stg = (_Float16*)(lds + O_S);

    const int tid = threadIdx.x;
    const int m   = blockIdx.x >> 5;   // member: bid%8 == G%8 for all members -> same XCD L2
    const int G   = blockIdx.x & 31;   // group (4 batch rows)
    const int jm  = m * SLICE;
    const int p   = tid;               // pass-2 / state column (0..511)

    // pass-1 thread mapping: wave w -> row r1, 32-j block; lane bit5 splits i into halves
    const int w    = tid >> 6;
    const int r1   = w >> 1;
    const int jj1  = (w & 1) * 32 + (tid & 31);
    const int half = (tid >> 5) & 1;

    // ---- one-time: load + fp16-convert weight col-slice into LDS, two layouts ----
    for (int it = 0; it < 8; ++it) {
        int gidx = it * 512 + tid;
        int i8 = gidx >> 6, j = gidx & 63;          // lanes run over j -> coalesced
        h8v wv;
        #pragma unroll
        for (int e = 0; e < 8; ++e)
            wv[e] = (_Float16)h2h[(size_t)(i8 * 8 + e) * NH + jm + j];
        w1p[i8 * 64 + j] = wv;
    }
    for (int it = 0; it < 8; ++it) {
        int gidx = it * 512 + tid;
        int pr = gidx >> 3, k = gidx & 7;           // lanes run over k,e -> coalesced
        const float* rp = h2h + (size_t)pr * NH + jm + k * 8;
        h8v wv;
        #pragma unroll
        for (int e = 0; e < 8; ++e) wv[e] = (_Float16)rp[e];
        w2p[pr * 8 + (k ^ (pr & 7))] = wv;          // XOR swizzle: conflict-free row reads
    }

    // zero hy for t=0
    #pragma unroll
    for (int r = 0; r < 4; ++r) hyH[r * NH + p] = (_Float16)0.f;

    unsigned long long* rb = recbuf + (size_t)G * 2048;  // [2 parity][512 p][2 pack]

    const float bj1 = bias[jm + jj1];

    const float* ivBase = out + (size_t)(4 * G) * T_STEPS * NH + p;
    float* outBase      = out + (size_t)(4 * G) * T_STEPS * NH + p;
    const bool writer = ((p >> 6) == m);   // this member writes cols [jm, jm+64)

    float hy[4] = {0.f, 0.f, 0.f, 0.f};
    float hz[4] = {0.f, 0.f, 0.f, 0.f};
    float hyPrev[4] = {0.f, 0.f, 0.f, 0.f};
    int pvA[4] = {0, 0, 0, 0};   // prev biased quantized partials, even parity
    int pvB[4] = {0, 0, 0, 0};   // prev biased quantized partials, odd parity

    // prologue: iv(0)
    float iv[4];
    #pragma unroll
    for (int r = 0; r < 4; ++r) iv[r] = ivBase[(size_t)r * T_STEPS * NH];

    __syncthreads();   // weights + hyH ready

    for (int t = 0; t < T_STEPS; ++t) {
        // prefetch iv(t+1): slot untouched until peers pass ladder(t) (which needs our adds,
        // which follow the vmcnt(0) drain of these loads) -> race-free, latency hidden
        float ivn[4] = {0.f, 0.f, 0.f, 0.f};
        if (t + 1 < T_STEPS) {
            #pragma unroll
            for (int r = 0; r < 4; ++r)
                ivn[r] = ivBase[((size_t)r * T_STEPS + (t + 1)) * NH];
        }

        // ---- pass 1: z[r1][jm+jj1], bit5 i-split + shfl_xor(32) reduce ----
        {
            float acc = 0.f;
            const _Float16* hyRow = hyH + r1 * NH + half * 256;   // lane-uniform per half
            const h8v* wBase = w1p + (half * 32) * 64 + jj1;      // contiguous per 32-lane half
            #pragma unroll 8
            for (int kk = 0; kk < 32; ++kk) {
                h8v wv = wBase[kk * 64];
                h8v av = *(const h8v*)(hyRow + kk * 8);
                h2v wA = {wv[0], wv[1]}, wB = {wv[2], wv[3]},
                    wC = {wv[4], wv[5]}, wD = {wv[6], wv[7]};
                h2v aA = {av[0], av[1]}, aB = {av[2], av[3]},
                    aC = {av[4], av[5]}, aD = {av[6], av[7]};
                acc = FDOT2(wA, aA, acc); acc = FDOT2(wB, aB, acc);
                acc = FDOT2(wC, aC, acc); acc = FDOT2(wD, aD, acc);
            }
            float tot = acc + __shfl_xor(acc, 32);
            float sv = tanhf(tot + bj1);
            if (half == 0) stg[r1 * 64 + jj1] = (_Float16)sv;
        }
        __syncthreads();   // A: stg ready

        // ---- pass 2: partial rec[r][p] over own j-slice, for ALL 512 p ----
        float acc[4] = {0.f, 0.f, 0.f, 0.f};
        {
            const int sw = p & 7;
            #pragma unroll
            for (int k = 0; k < 8; ++k) {
                h8v wv = w2p[p * 8 + (k ^ sw)];
                h2v wA = {wv[0], wv[1]}, wB = {wv[2], wv[3]},
                    wC = {wv[4], wv[5]}, wD = {wv[6], wv[7]};
                #pragma unroll
                for (int r = 0; r < 4; ++r) {
                    h8v sv = *(const h8v*)(stg + r * 64 + k * 8);   // lane-uniform broadcast
                    h2v sA = {sv[0], sv[1]}, sB = {sv[2], sv[3]},
                        sC = {sv[4], sv[5]}, sD = {sv[6], sv[7]};
                    float a = acc[r];
                    a = FDOT2(wA, sA, a); a = FDOT2(wB, sB, a);
                    a = FDOT2(wC, sC, a); a = FDOT2(wD, sD, a);
                    acc[r] = a;
                }
            }
        }

        // ---- biased quantize, diff, pack 2 rows per u64 ----
        int Q0 = (int)rintf(acc[0] * SCALE_F) + BIGC;
        int Q1 = (int)rintf(acc[1] * SCALE_F) + BIGC;
        int Q2 = (int)rintf(acc[2] * SCALE_F) + BIGC;
        int Q3 = (int)rintf(acc[3] * SCALE_F) + BIGC;
        int d0, d1, d2, d3;
        if (t & 1) {
            d0 = Q0 - pvB[0]; pvB[0] = Q0;  d1 = Q1 - pvB[1]; pvB[1] = Q1;
            d2 = Q2 - pvB[2]; pvB[2] = Q2;  d3 = Q3 - pvB[3]; pvB[3] = Q3;
        } else {
            d0 = Q0 - pvA[0]; pvA[0] = Q0;  d1 = Q1 - pvA[1]; pvA[1] = Q1;
            d2 = Q2 - pvA[2]; pvA[2] = Q2;  d3 = Q3 - pvA[3]; pvA[3] = Q3;
        }
        unsigned long long c0 = (1ull << 50)
            + ((unsigned long long)(long long)d0 << 25) + (unsigned long long)(long long)d1;
        unsigned long long c1 = (1ull << 50)
            + ((unsigned long long)(long long)d2 << 25) + (unsigned long long)(long long)d3;

        const int par = t & 1;
        unsigned long long* e0 = rb + par * 1024 + p * 2;   // adjacent pair: one cache line
        unsigned long long* e1 = e0 + 1;

        // drain ivn loads (WAR fence vs peers' out overwrite), then publish
        asm volatile("s_waitcnt vmcnt(0)" ::: "memory");
        __hip_atomic_fetch_add(e0, c0, __ATOMIC_RELAXED, __HIP_MEMORY_SCOPE_AGENT);
        __hip_atomic_fetch_add(e1, c1, __ATOMIC_RELAXED, __HIP_MEMORY_SCOPE_AGENT);

        // deferred out store of hy(t-1): ack drains under the poll, not under a barrier
        if (writer && t > 0) {
            #pragma unroll
            for (int r = 0; r < 4; ++r)
                outBase[((size_t)r * T_STEPS + (t - 1)) * NH] = hyPrev[r];
        }

        // ---- poll: raw count in bits 50-63 (exact; fields can't borrow) ----
        const unsigned int expc = 8u * (unsigned int)((t >> 1) + 1);
        unsigned long long v0, v1;
        __builtin_amdgcn_s_sleep(2);
        for (;;) {
            v0 = __hip_atomic_load(e0, __ATOMIC_RELAXED, __HIP_MEMORY_SCOPE_AGENT);
            v1 = __hip_atomic_load(e1, __ATOMIC_RELAXED, __HIP_MEMORY_SCOPE_AGENT);
            if ((unsigned int)(v0 >> 50) >= expc && (unsigned int)(v1 >> 50) >= expc) break;
            __builtin_amdgcn_s_sleep(1);
        }

        // ---- decode: mask + unbias (fields provably in [0, 2^25)) ----
        float rec[4];
        rec[0] = (float)((int)((v0 >> 25) & 0x1FFFFFFull) - BIAS8) * INV_SCALE;
        rec[1] = (float)((int)(v0 & 0x1FFFFFFull) - BIAS8) * INV_SCALE;
        rec[2] = (float)((int)((v1 >> 25) & 0x1FFFFFFull) - BIAS8) * INV_SCALE;
        rec[3] = (float)((int)(v1 & 0x1FFFFFFull) - BIAS8) * INV_SCALE;

        // ---- identical full update on every member ----
        #pragma unroll
        for (int r = 0; r < 4; ++r) {
            hz[r] = hz[r] + DT * (iv[r] - rec[r] - hy[r] - hz[r]);
            hy[r] = hy[r] + DT * hz[r];
            hyH[r * NH + p] = (_Float16)hy[r];
            hyPrev[r] = hy[r];
            iv[r] = ivn[r];
        }
        __syncthreads();   // D: hyH ready for next pass 1
    }

    // flush deferred store for t=1023, then hy_f (concatenated after all_states)
    if (writer) {
        #pragma unroll
        for (int r = 0; r < 4; ++r)
            outBase[((size_t)r * T_STEPS + (T_STEPS - 1)) * NH] = hyPrev[r];
        #pragma unroll
        for (int r = 0; r < 4; ++r)
            out[(size_t)NB * T_STEPS * NH + (size_t)(4 * G + r) * NH + p] = hyPrev[r];
    }
}

// ---------- launch ----------
extern "C" void kernel_launch(void* const* d_in, const int* in_sizes, int n_in,
                              void* d_out, int out_size, void* d_ws, size_t ws_size,
                              hipStream_t stream) {
    const float* x    = (const float*)d_in[0];   // [128,1024,64]
    const float* x2h  = (const float*)d_in[1];   // [64,512]
    const float* h2h  = (const float*)d_in[2];   // [512,512]
    const float* bias = (const float*)d_in[3];   // [512]
    float* out = (float*)d_out;

    // ws layout: recbuf only: 32 groups x 2048 u64 = 512 KB
    unsigned long long* recbuf = (unsigned long long*)d_ws;

    hipMemsetAsync(d_ws, 0, 32 * 2048 * sizeof(unsigned long long), stream);

    i2h_kernel<<<8192, 512, 0, stream>>>(x, x2h, out);

    hipFuncSetAttribute((const void*)recur7,
                        hipFuncAttributeMaxDynamicSharedMemorySize, LDS_BYTES);
    recur7<<<256, 512, LDS_BYTES, stream>>>(h2h, bias, out, recbuf);
}